// Round 1
// baseline (4618.932 us; speedup 1.0000x reference)
//
#include <hip/hip_runtime.h>
#include <math.h>

#define NN 10000
#define EE 160000

#define RS128 0.08838834764831845f   // 1/sqrt(128)
#define RS384 0.05103103630798287f   // 1/sqrt(384)
#define RS32  0.17677669529663687f   // 1/sqrt(32)
#define R3    0.57735026918962576f   // 1/sqrt(3)
#define C1V   0.86602540378443865f   // sqrt(3)/2

__device__ __forceinline__ float sspf(float x) {
    // softplus(x) - log(2), numerically stable
    return fmaxf(x, 0.0f) + log1pf(__expf(-fabsf(x))) - 0.69314718055994530942f;
}

// out = irrep_linear(X, W0, b0, W1) : s = Xs @ W0/sqrt(128) + b0 ; v = einsum(num,uv->nvm)/sqrt(128)
__global__ __launch_bounds__(256) void k_irrep(
    const float* __restrict__ X, const float* __restrict__ W0,
    const float* __restrict__ b0, const float* __restrict__ W1,
    float* __restrict__ out) {
    __shared__ float xs_t[16][128];
    __shared__ float xv_t[16][384];
    const int t = threadIdx.x;
    const int nb = blockIdx.x * 16;
    for (int idx = t; idx < 16 * 512; idx += 256) {
        int n = idx >> 9, c = idx & 511;
        float v = X[(size_t)(nb + n) * 512 + c];
        if (c < 128) xs_t[n][c] = v; else xv_t[n][c - 128] = v;
    }
    __syncthreads();
    const int col = t & 127, half = t >> 7;
    float accs[8] = {0, 0, 0, 0, 0, 0, 0, 0};
    float accv[24] = {0};
    for (int u = 0; u < 128; ++u) {
        float w0 = W0[u * 128 + col];
        float w1 = W1[u * 128 + col];
#pragma unroll
        for (int i = 0; i < 8; ++i) {
            int n = half * 8 + i;
            accs[i] = fmaf(xs_t[n][u], w0, accs[i]);
            accv[3 * i + 0] = fmaf(xv_t[n][3 * u + 0], w1, accv[3 * i + 0]);
            accv[3 * i + 1] = fmaf(xv_t[n][3 * u + 1], w1, accv[3 * i + 1]);
            accv[3 * i + 2] = fmaf(xv_t[n][3 * u + 2], w1, accv[3 * i + 2]);
        }
    }
    float bias = b0[col];
#pragma unroll
    for (int i = 0; i < 8; ++i) {
        size_t gn = (size_t)(nb + half * 8 + i) * 512;
        out[gn + col] = accs[i] * RS128 + bias;
        out[gn + 128 + 3 * col + 0] = accv[3 * i + 0] * RS128;
        out[gn + 128 + 3 * col + 1] = accv[3 * i + 1] * RS128;
        out[gn + 128 + 3 * col + 2] = accv[3 * i + 2] * RS128;
    }
}

// self_x = irrep_linear(norm_gate(x), Wn0, bn0, Wn1); written to BOTH selfx and accb (seed for segsum)
__global__ __launch_bounds__(256) void k_self(
    const float* __restrict__ X,
    const float* __restrict__ ngW1, const float* __restrict__ ngb1,
    const float* __restrict__ ngW2, const float* __restrict__ ngb2,
    const float* __restrict__ Wn0, const float* __restrict__ bn0,
    const float* __restrict__ Wn1,
    float* __restrict__ selfx, float* __restrict__ accb) {
    __shared__ float xv_t[16][384];
    __shared__ float f0_t[16][256];   // f0 first, then g
    __shared__ float t1_t[16][256];
    const int t = threadIdx.x;
    const int nb = blockIdx.x * 16;
    for (int idx = t; idx < 16 * 512; idx += 256) {
        int n = idx >> 9, c = idx & 511;
        float v = X[(size_t)(nb + n) * 512 + c];
        if (c < 128) f0_t[n][c] = v; else xv_t[n][c - 128] = v;
    }
    __syncthreads();
    // norm of vectors -> f0[:,128:]
    for (int idx = t; idx < 16 * 128; idx += 256) {
        int n = idx >> 7, u = idx & 127;
        float a = xv_t[n][3 * u], b = xv_t[n][3 * u + 1], c = xv_t[n][3 * u + 2];
        f0_t[n][128 + u] = sqrtf(fmaf(a, a, fmaf(b, b, fmaf(c, c, 1e-12f))));
    }
    __syncthreads();
    // t1 = silu(f0 @ ngW1 + b1)
    {
        float acc[16] = {0};
        for (int k = 0; k < 256; ++k) {
            float w = ngW1[k * 256 + t];
#pragma unroll
            for (int n = 0; n < 16; ++n) acc[n] = fmaf(f0_t[n][k], w, acc[n]);
        }
        float b1 = ngb1[t];
#pragma unroll
        for (int n = 0; n < 16; ++n) {
            float z = acc[n] + b1;
            t1_t[n][t] = z * (1.0f / (1.0f + __expf(-z)));
        }
    }
    __syncthreads();
    // g = t1 @ ngW2 + b2 -> overwrite f0_t
    {
        float acc[16] = {0};
        for (int k = 0; k < 256; ++k) {
            float w = ngW2[k * 256 + t];
#pragma unroll
            for (int n = 0; n < 16; ++n) acc[n] = fmaf(t1_t[n][k], w, acc[n]);
        }
        float b2 = ngb2[t];
#pragma unroll
        for (int n = 0; n < 16; ++n) f0_t[n][t] = acc[n] + b2;
    }
    __syncthreads();
    // gate vectors in place
    for (int idx = t; idx < 16 * 384; idx += 256) {
        int n = idx / 384, j = idx % 384;
        xv_t[n][j] *= f0_t[n][128 + j / 3];
    }
    __syncthreads();
    // irrep_linear with Wn
    const int col = t & 127, half = t >> 7;
    float accs[8] = {0, 0, 0, 0, 0, 0, 0, 0};
    float accv[24] = {0};
    for (int u = 0; u < 128; ++u) {
        float w0 = Wn0[u * 128 + col];
        float w1 = Wn1[u * 128 + col];
#pragma unroll
        for (int i = 0; i < 8; ++i) {
            int n = half * 8 + i;
            accs[i] = fmaf(f0_t[n][u], w0, accs[i]);
            accv[3 * i + 0] = fmaf(xv_t[n][3 * u + 0], w1, accv[3 * i + 0]);
            accv[3 * i + 1] = fmaf(xv_t[n][3 * u + 1], w1, accv[3 * i + 1]);
            accv[3 * i + 2] = fmaf(xv_t[n][3 * u + 2], w1, accv[3 * i + 2]);
        }
    }
    float bias = bn0[col];
#pragma unroll
    for (int i = 0; i < 8; ++i) {
        size_t gn = (size_t)(nb + half * 8 + i) * 512;
        float s = accs[i] * RS128 + bias;
        float v0 = accv[3 * i + 0] * RS128;
        float v1 = accv[3 * i + 1] * RS128;
        float v2 = accv[3 * i + 2] * RS128;
        selfx[gn + col] = s;
        selfx[gn + 128 + 3 * col + 0] = v0;
        selfx[gn + 128 + 3 * col + 1] = v1;
        selfx[gn + 128 + 3 * col + 2] = v2;
        accb[gn + col] = s;
        accb[gn + 128 + 3 * col + 0] = v0;
        accb[gn + 128 + 3 * col + 1] = v1;
        accb[gn + 128 + 3 * col + 2] = v2;
    }
}

// per-edge: s0 -> two MLPs -> w -> tensor product -> atomic segment sum
__global__ __launch_bounds__(256) void k_edge(
    const float* __restrict__ pre_x, const float* __restrict__ selfx,
    const int* __restrict__ edge_index, const float* __restrict__ edge_attr,
    const float* __restrict__ edge_sh,
    const float* __restrict__ fcnW1, const float* __restrict__ fcnW2,
    const float* __restrict__ l0W1, const float* __restrict__ l0W2,
    float* __restrict__ accb) {
    __shared__ float s0[32][385];
    __shared__ float ea[32][33];
    __shared__ float h[32][66];
    __shared__ float shl[32][4];
    __shared__ int dstl[32], srcl[32];
    const int t = threadIdx.x;
    const int eb = blockIdx.x * 32;

    if (t < 32) dstl[t] = edge_index[eb + t];
    else if (t < 64) srcl[t - 32] = edge_index[EE + eb + (t - 32)];
    if (t >= 64 && t < 192) {
        int i = t - 64;
        shl[i >> 2][i & 3] = edge_sh[(size_t)eb * 4 + i];
    }
    for (int idx = t; idx < 1024; idx += 256)
        ea[idx >> 5][idx & 31] = edge_attr[(size_t)eb * 32 + idx];
    __syncthreads();

    // phase A: s0 = [pre_dst_s | pre_src_s | ip]
    for (int e = 0; e < 32; ++e) {
        float v = (t < 128) ? pre_x[(size_t)dstl[e] * 512 + t]
                            : pre_x[(size_t)srcl[e] * 512 + (t - 128)];
        s0[e][t] = v;
    }
    {
        const int e = t >> 3, u0 = t & 7;
        const float* pd = pre_x + (size_t)dstl[e] * 512 + 128;
        const float* ps = pre_x + (size_t)srcl[e] * 512 + 128;
#pragma unroll 4
        for (int i = 0; i < 16; ++i) {
            int u = u0 + 8 * i;
            float s = pd[3 * u] * ps[3 * u] + pd[3 * u + 1] * ps[3 * u + 1] + pd[3 * u + 2] * ps[3 * u + 2];
            s0[e][256 + u] = s * R3;
        }
    }
    __syncthreads();

    // phase B: hidden units (32 each path), ssp activation
    {
        const int e = t & 31;
        const int jq = t >> 5;  // 0..7, owns cols 4jq..4jq+3
        float a0 = 0, a1 = 0, a2 = 0, a3 = 0;
#pragma unroll 4
        for (int k = 0; k < 384; ++k) {
            float sv = s0[e][k];
            const float4 w = *(const float4*)(l0W1 + k * 32 + 4 * jq);
            a0 = fmaf(sv, w.x, a0); a1 = fmaf(sv, w.y, a1);
            a2 = fmaf(sv, w.z, a2); a3 = fmaf(sv, w.w, a3);
        }
        h[e][4 * jq + 0] = sspf(a0 * RS384);
        h[e][4 * jq + 1] = sspf(a1 * RS384);
        h[e][4 * jq + 2] = sspf(a2 * RS384);
        h[e][4 * jq + 3] = sspf(a3 * RS384);
        float c0 = 0, c1 = 0, c2 = 0, c3 = 0;
#pragma unroll
        for (int k = 0; k < 32; ++k) {
            float av = ea[e][k];
            const float4 w = *(const float4*)(fcnW1 + k * 32 + 4 * jq);
            c0 = fmaf(av, w.x, c0); c1 = fmaf(av, w.y, c1);
            c2 = fmaf(av, w.z, c2); c3 = fmaf(av, w.w, c3);
        }
        h[e][32 + 4 * jq + 0] = sspf(c0 * RS32);
        h[e][32 + 4 * jq + 1] = sspf(c1 * RS32);
        h[e][32 + 4 * jq + 2] = sspf(c2 * RS32);
        h[e][32 + 4 * jq + 3] = sspf(c3 * RS32);
    }
    __syncthreads();

    // phase C: w = (ha@fcnW2)*(h1@l0W2)/32 ; tensor product ; atomic scatter
    {
        const int e = t >> 3;
        const int ublk = t & 7;
        const int dst = dstl[e];
        const int src = srcl[e];
        const float sh0v = shl[e][0], s1x = shl[e][1], s1y = shl[e][2], s1z = shl[e][3];
        const float* xsrow = selfx + (size_t)src * 512;
        float* accd = accb + (size_t)dst * 512;
        for (int q = 0; q < 4; ++q) {
            const int u = ublk * 16 + q * 4;
            float4 A0 = {0, 0, 0, 0}, A1 = {0, 0, 0, 0}, A2 = {0, 0, 0, 0}, A3 = {0, 0, 0, 0};
            float4 B0 = {0, 0, 0, 0}, B1 = {0, 0, 0, 0}, B2 = {0, 0, 0, 0}, B3 = {0, 0, 0, 0};
#pragma unroll 4
            for (int k = 0; k < 32; ++k) {
                float h1_ = h[e][k];
                float ha_ = h[e][32 + k];
                const float4 wf0 = *(const float4*)(fcnW2 + k * 512 + 0 * 128 + u);
                const float4 wf1 = *(const float4*)(fcnW2 + k * 512 + 1 * 128 + u);
                const float4 wf2 = *(const float4*)(fcnW2 + k * 512 + 2 * 128 + u);
                const float4 wf3 = *(const float4*)(fcnW2 + k * 512 + 3 * 128 + u);
                const float4 wl0 = *(const float4*)(l0W2 + k * 512 + 0 * 128 + u);
                const float4 wl1 = *(const float4*)(l0W2 + k * 512 + 1 * 128 + u);
                const float4 wl2 = *(const float4*)(l0W2 + k * 512 + 2 * 128 + u);
                const float4 wl3 = *(const float4*)(l0W2 + k * 512 + 3 * 128 + u);
                A0.x = fmaf(ha_, wf0.x, A0.x); A0.y = fmaf(ha_, wf0.y, A0.y);
                A0.z = fmaf(ha_, wf0.z, A0.z); A0.w = fmaf(ha_, wf0.w, A0.w);
                A1.x = fmaf(ha_, wf1.x, A1.x); A1.y = fmaf(ha_, wf1.y, A1.y);
                A1.z = fmaf(ha_, wf1.z, A1.z); A1.w = fmaf(ha_, wf1.w, A1.w);
                A2.x = fmaf(ha_, wf2.x, A2.x); A2.y = fmaf(ha_, wf2.y, A2.y);
                A2.z = fmaf(ha_, wf2.z, A2.z); A2.w = fmaf(ha_, wf2.w, A2.w);
                A3.x = fmaf(ha_, wf3.x, A3.x); A3.y = fmaf(ha_, wf3.y, A3.y);
                A3.z = fmaf(ha_, wf3.z, A3.z); A3.w = fmaf(ha_, wf3.w, A3.w);
                B0.x = fmaf(h1_, wl0.x, B0.x); B0.y = fmaf(h1_, wl0.y, B0.y);
                B0.z = fmaf(h1_, wl0.z, B0.z); B0.w = fmaf(h1_, wl0.w, B0.w);
                B1.x = fmaf(h1_, wl1.x, B1.x); B1.y = fmaf(h1_, wl1.y, B1.y);
                B1.z = fmaf(h1_, wl1.z, B1.z); B1.w = fmaf(h1_, wl1.w, B1.w);
                B2.x = fmaf(h1_, wl2.x, B2.x); B2.y = fmaf(h1_, wl2.y, B2.y);
                B2.z = fmaf(h1_, wl2.z, B2.z); B2.w = fmaf(h1_, wl2.w, B2.w);
                B3.x = fmaf(h1_, wl3.x, B3.x); B3.y = fmaf(h1_, wl3.y, B3.y);
                B3.z = fmaf(h1_, wl3.z, B3.z); B3.w = fmaf(h1_, wl3.w, B3.w);
            }
            const float4 x0 = *(const float4*)(xsrow + u);
            const float4 xv0 = *(const float4*)(xsrow + 128 + 3 * u);
            const float4 xv1 = *(const float4*)(xsrow + 128 + 3 * u + 4);
            const float4 xv2 = *(const float4*)(xsrow + 128 + 3 * u + 8);
            const float inv32 = 1.0f / 32.0f;
            float W1v[4] = {A0.x * B0.x * inv32, A0.y * B0.y * inv32, A0.z * B0.z * inv32, A0.w * B0.w * inv32};
            float W2v[4] = {A1.x * B1.x * inv32, A1.y * B1.y * inv32, A1.z * B1.z * inv32, A1.w * B1.w * inv32};
            float W3v[4] = {A2.x * B2.x * inv32, A2.y * B2.y * inv32, A2.z * B2.z * inv32, A2.w * B2.w * inv32};
            float W4v[4] = {A3.x * B3.x * inv32, A3.y * B3.y * inv32, A3.z * B3.z * inv32, A3.w * B3.w * inv32};
            float xs0a[4] = {x0.x, x0.y, x0.z, x0.w};
            float xv[4][3] = {{xv0.x, xv0.y, xv0.z}, {xv0.w, xv1.x, xv1.y},
                              {xv1.z, xv1.w, xv2.x}, {xv2.y, xv2.z, xv2.w}};
#pragma unroll
            for (int j = 0; j < 4; ++j) {
                float x0s = xs0a[j];
                float dv = xv[j][0] * s1x + xv[j][1] * s1y + xv[j][2] * s1z;
                float o0 = 0.5f * (W1v[j] * x0s * sh0v + W4v[j] * dv * R3);
                atomicAdd(accd + (u + j), o0);
                atomicAdd(accd + 128 + 3 * (u + j) + 0, C1V * (W2v[j] * x0s * s1x + W3v[j] * xv[j][0] * sh0v));
                atomicAdd(accd + 128 + 3 * (u + j) + 1, C1V * (W2v[j] * x0s * s1y + W3v[j] * xv[j][1] * sh0v));
                atomicAdd(accd + 128 + 3 * (u + j) + 2, C1V * (W2v[j] * x0s * s1z + W3v[j] * xv[j][2] * sh0v));
            }
        }
    }
}

extern "C" void kernel_launch(void* const* d_in, const int* in_sizes, int n_in,
                              void* d_out, int out_size, void* d_ws, size_t ws_size,
                              hipStream_t stream) {
    const float* x = (const float*)d_in[0];
    const int* edge_index = (const int*)d_in[1];
    const float* edge_attr = (const float*)d_in[2];
    const float* edge_sh = (const float*)d_in[3];
    const float* Wp0 = (const float*)d_in[4];
    const float* bp0 = (const float*)d_in[5];
    const float* Wp1 = (const float*)d_in[6];
    const float* ngW1 = (const float*)d_in[7];
    const float* ngb1 = (const float*)d_in[8];
    const float* ngW2 = (const float*)d_in[9];
    const float* ngb2 = (const float*)d_in[10];
    const float* Wn0 = (const float*)d_in[11];
    const float* bn0 = (const float*)d_in[12];
    const float* Wn1 = (const float*)d_in[13];
    const float* fcnW1 = (const float*)d_in[14];
    const float* fcnW2 = (const float*)d_in[15];
    const float* l0W1 = (const float*)d_in[16];
    const float* l0W2 = (const float*)d_in[17];
    const float* Wo0 = (const float*)d_in[18];
    const float* bo0 = (const float*)d_in[19];
    const float* Wo1 = (const float*)d_in[20];

    float* out = (float*)d_out;
    float* selfx = (float*)d_ws;
    float* accb = selfx + (size_t)NN * 512;
    float* prex = out;  // reuse d_out as pre_x scratch (overwritten by final kernel)

    k_irrep<<<NN / 16, 256, 0, stream>>>(x, Wp0, bp0, Wp1, prex);
    k_self<<<NN / 16, 256, 0, stream>>>(x, ngW1, ngb1, ngW2, ngb2, Wn0, bn0, Wn1, selfx, accb);
    k_edge<<<EE / 32, 256, 0, stream>>>(prex, selfx, edge_index, edge_attr, edge_sh,
                                        fcnW1, fcnW2, l0W1, l0W2, accb);
    k_irrep<<<NN / 16, 256, 0, stream>>>(accb, Wo0, bo0, Wo1, out);
}

// Round 2
// 1060.487 us; speedup vs baseline: 4.3555x; 4.3555x over previous
//
#include <hip/hip_runtime.h>
#include <math.h>

#define NN 10000
#define EE 160000

#define RS128 0.08838834764831845f   // 1/sqrt(128)
#define RS384 0.05103103630798287f   // 1/sqrt(384)
#define RS32  0.17677669529663687f   // 1/sqrt(32)
#define R3    0.57735026918962576f   // 1/sqrt(3)
#define C1V   0.86602540378443865f   // sqrt(3)/2

__device__ __forceinline__ float sspf(float x) {
    // softplus(x) - log(2), numerically stable
    return fmaxf(x, 0.0f) + log1pf(__expf(-fabsf(x))) - 0.69314718055994530942f;
}

// out = irrep_linear(X, W0, b0, W1). In-place safe per block (stages tile first).
__global__ __launch_bounds__(256) void k_irrep(
    const float* __restrict__ X, const float* __restrict__ W0,
    const float* __restrict__ b0, const float* __restrict__ W1,
    float* __restrict__ out) {
    __shared__ float xs_t[16][128];
    __shared__ float xv_t[16][384];
    const int t = threadIdx.x;
    const int nb = blockIdx.x * 16;
    for (int idx = t; idx < 16 * 512; idx += 256) {
        int n = idx >> 9, c = idx & 511;
        float v = X[(size_t)(nb + n) * 512 + c];
        if (c < 128) xs_t[n][c] = v; else xv_t[n][c - 128] = v;
    }
    __syncthreads();
    const int col = t & 127, half = t >> 7;
    float accs[8] = {0, 0, 0, 0, 0, 0, 0, 0};
    float accv[24] = {0};
    for (int u = 0; u < 128; ++u) {
        float w0 = W0[u * 128 + col];
        float w1 = W1[u * 128 + col];
#pragma unroll
        for (int i = 0; i < 8; ++i) {
            int n = half * 8 + i;
            accs[i] = fmaf(xs_t[n][u], w0, accs[i]);
            accv[3 * i + 0] = fmaf(xv_t[n][3 * u + 0], w1, accv[3 * i + 0]);
            accv[3 * i + 1] = fmaf(xv_t[n][3 * u + 1], w1, accv[3 * i + 1]);
            accv[3 * i + 2] = fmaf(xv_t[n][3 * u + 2], w1, accv[3 * i + 2]);
        }
    }
    float bias = b0[col];
#pragma unroll
    for (int i = 0; i < 8; ++i) {
        size_t gn = (size_t)(nb + half * 8 + i) * 512;
        out[gn + col] = accs[i] * RS128 + bias;
        out[gn + 128 + 3 * col + 0] = accv[3 * i + 0] * RS128;
        out[gn + 128 + 3 * col + 1] = accv[3 * i + 1] * RS128;
        out[gn + 128 + 3 * col + 2] = accv[3 * i + 2] * RS128;
    }
}

// self_x = irrep_linear(norm_gate(x), Wn0, bn0, Wn1)
__global__ __launch_bounds__(256) void k_self(
    const float* __restrict__ X,
    const float* __restrict__ ngW1, const float* __restrict__ ngb1,
    const float* __restrict__ ngW2, const float* __restrict__ ngb2,
    const float* __restrict__ Wn0, const float* __restrict__ bn0,
    const float* __restrict__ Wn1,
    float* __restrict__ selfx) {
    __shared__ float xv_t[16][384];
    __shared__ float f0_t[16][256];   // f0 first, then g
    __shared__ float t1_t[16][256];
    const int t = threadIdx.x;
    const int nb = blockIdx.x * 16;
    for (int idx = t; idx < 16 * 512; idx += 256) {
        int n = idx >> 9, c = idx & 511;
        float v = X[(size_t)(nb + n) * 512 + c];
        if (c < 128) f0_t[n][c] = v; else xv_t[n][c - 128] = v;
    }
    __syncthreads();
    for (int idx = t; idx < 16 * 128; idx += 256) {
        int n = idx >> 7, u = idx & 127;
        float a = xv_t[n][3 * u], b = xv_t[n][3 * u + 1], c = xv_t[n][3 * u + 2];
        f0_t[n][128 + u] = sqrtf(fmaf(a, a, fmaf(b, b, fmaf(c, c, 1e-12f))));
    }
    __syncthreads();
    {
        float acc[16] = {0};
        for (int k = 0; k < 256; ++k) {
            float w = ngW1[k * 256 + t];
#pragma unroll
            for (int n = 0; n < 16; ++n) acc[n] = fmaf(f0_t[n][k], w, acc[n]);
        }
        float b1 = ngb1[t];
#pragma unroll
        for (int n = 0; n < 16; ++n) {
            float z = acc[n] + b1;
            t1_t[n][t] = z * (1.0f / (1.0f + __expf(-z)));
        }
    }
    __syncthreads();
    {
        float acc[16] = {0};
        for (int k = 0; k < 256; ++k) {
            float w = ngW2[k * 256 + t];
#pragma unroll
            for (int n = 0; n < 16; ++n) acc[n] = fmaf(t1_t[n][k], w, acc[n]);
        }
        float b2 = ngb2[t];
#pragma unroll
        for (int n = 0; n < 16; ++n) f0_t[n][t] = acc[n] + b2;
    }
    __syncthreads();
    for (int idx = t; idx < 16 * 384; idx += 256) {
        int n = idx / 384, j = idx % 384;
        xv_t[n][j] *= f0_t[n][128 + j / 3];
    }
    __syncthreads();
    const int col = t & 127, half = t >> 7;
    float accs[8] = {0, 0, 0, 0, 0, 0, 0, 0};
    float accv[24] = {0};
    for (int u = 0; u < 128; ++u) {
        float w0 = Wn0[u * 128 + col];
        float w1 = Wn1[u * 128 + col];
#pragma unroll
        for (int i = 0; i < 8; ++i) {
            int n = half * 8 + i;
            accs[i] = fmaf(f0_t[n][u], w0, accs[i]);
            accv[3 * i + 0] = fmaf(xv_t[n][3 * u + 0], w1, accv[3 * i + 0]);
            accv[3 * i + 1] = fmaf(xv_t[n][3 * u + 1], w1, accv[3 * i + 1]);
            accv[3 * i + 2] = fmaf(xv_t[n][3 * u + 2], w1, accv[3 * i + 2]);
        }
    }
    float bias = bn0[col];
#pragma unroll
    for (int i = 0; i < 8; ++i) {
        size_t gn = (size_t)(nb + half * 8 + i) * 512;
        selfx[gn + col] = accs[i] * RS128 + bias;
        selfx[gn + 128 + 3 * col + 0] = accv[3 * i + 0] * RS128;
        selfx[gn + 128 + 3 * col + 1] = accv[3 * i + 1] * RS128;
        selfx[gn + 128 + 3 * col + 2] = accv[3 * i + 2] * RS128;
    }
}

// ---- CSR build ----
__global__ __launch_bounds__(256) void k_deg(const int* __restrict__ ei, int* __restrict__ deg) {
    int e = blockIdx.x * 256 + threadIdx.x;
    if (e < EE) atomicAdd(&deg[ei[e]], 1);
}

__global__ __launch_bounds__(1024) void k_scan(const int* __restrict__ deg, int* __restrict__ row_ptr) {
    __shared__ int part[1024];
    const int t = threadIdx.x;
    const int base = t * 10;
    int loc[10];
    int s = 0;
#pragma unroll
    for (int i = 0; i < 10; ++i) {
        int idx = base + i;
        int d = (idx < NN) ? deg[idx] : 0;
        loc[i] = s;
        s += d;
    }
    part[t] = s;
    __syncthreads();
    for (int off = 1; off < 1024; off <<= 1) {
        int v = (t >= off) ? part[t - off] : 0;
        __syncthreads();
        part[t] += v;
        __syncthreads();
    }
    int excl = (t > 0) ? part[t - 1] : 0;
#pragma unroll
    for (int i = 0; i < 10; ++i) {
        int idx = base + i;
        if (idx <= NN) row_ptr[idx] = excl + loc[i];
    }
}

__global__ __launch_bounds__(256) void k_fill(const int* __restrict__ ei,
                                              const int* __restrict__ row_ptr,
                                              int* __restrict__ cursor,
                                              int* __restrict__ csr_eid) {
    int e = blockIdx.x * 256 + threadIdx.x;
    if (e < EE) {
        int d = ei[e];
        int pos = atomicAdd(&cursor[d], 1);
        csr_eid[row_ptr[d] + pos] = e;
    }
}

// ---- per-dst edge compute + aggregate (no atomics) ----
__global__ __launch_bounds__(256) void k_gather(
    const float* __restrict__ prex, const float* __restrict__ selfx,
    const int* __restrict__ edge_index, const float* __restrict__ edge_attr,
    const float* __restrict__ edge_sh,
    const int* __restrict__ row_ptr, const int* __restrict__ csr_eid,
    const float* __restrict__ fcnW1, const float* __restrict__ fcnW2,
    const float* __restrict__ l0W1, const float* __restrict__ l0W2,
    float* __restrict__ accb) {
    const int dst = blockIdx.x;
    const int t = threadIdx.x;
    const int beg = row_ptr[dst];
    const int ne = row_ptr[dst + 1] - beg;

    __shared__ float dsts[128];
    __shared__ float dstv[384];
    __shared__ float s0[8][388];
    __shared__ float hh[8][64];
    __shared__ float shl[8][4];
    __shared__ int srcs[8];
    __shared__ int eidl[8];
    __shared__ float red[512];

    if (t < 128) dsts[t] = prex[(size_t)dst * 512 + t];
    for (int i = t; i < 384; i += 256) dstv[i] = prex[(size_t)dst * 512 + 128 + i];

    const int u = t & 127;
    const int half = t >> 7;
    float acc0 = 0, acc1 = 0, acc2 = 0, acc3 = 0;

    __syncthreads();

    for (int c0 = 0; c0 < ne; c0 += 8) {
        const int ce = min(8, ne - c0);
        if (t < 8) {
            int id = csr_eid[beg + c0 + ((t < ce) ? t : 0)];
            eidl[t] = id;
            srcs[t] = edge_index[EE + id];
            const float4 s = *(const float4*)(edge_sh + (size_t)id * 4);
            shl[t][0] = s.x; shl[t][1] = s.y; shl[t][2] = s.z; shl[t][3] = s.w;
        }
        __syncthreads();

        // build s0 = [dst_s | src_s | ip]
        for (int idx = t; idx < ce * 384; idx += 256) {
            int e = idx / 384, j = idx - e * 384;
            const int src = srcs[e];
            float v;
            if (j < 128) v = dsts[j];
            else if (j < 256) v = prex[(size_t)src * 512 + (j - 128)];
            else {
                int u2 = j - 256;
                const float* pv = prex + (size_t)src * 512 + 128 + 3 * u2;
                v = (dstv[3 * u2] * pv[0] + dstv[3 * u2 + 1] * pv[1] + dstv[3 * u2 + 2] * pv[2]) * R3;
            }
            s0[e][j] = v;
        }
        __syncthreads();

        // hidden: h1 (l0 path) and ha (fcn path)
        {
            const int e = t >> 5, k = t & 31;
            if (e < ce) {
                float a = 0;
#pragma unroll 4
                for (int j = 0; j < 384; ++j)
                    a = fmaf(s0[e][j], l0W1[j * 32 + k], a);
                hh[e][k] = sspf(a * RS384);
                float c = 0;
                const float* ear = edge_attr + (size_t)eidl[e] * 32;
#pragma unroll
                for (int j = 0; j < 32; ++j)
                    c = fmaf(ear[j], fcnW1[j * 32 + k], c);
                hh[e][32 + k] = sspf(c * RS32);
            }
        }
        __syncthreads();

        // phase C: per-thread owns column u; half handles edges {half, half+2, half+4, half+6}
        {
            float A1[4], A2[4], A3[4], A4[4], B1[4], B2[4], B3[4], B4[4];
#pragma unroll
            for (int i = 0; i < 4; ++i) {
                A1[i] = A2[i] = A3[i] = A4[i] = 0;
                B1[i] = B2[i] = B3[i] = B4[i] = 0;
            }
            for (int k = 0; k < 32; ++k) {
                const float wf1 = fcnW2[k * 512 + u];
                const float wf2 = fcnW2[k * 512 + 128 + u];
                const float wf3 = fcnW2[k * 512 + 256 + u];
                const float wf4 = fcnW2[k * 512 + 384 + u];
                const float wl1 = l0W2[k * 512 + u];
                const float wl2 = l0W2[k * 512 + 128 + u];
                const float wl3 = l0W2[k * 512 + 256 + u];
                const float wl4 = l0W2[k * 512 + 384 + u];
#pragma unroll
                for (int i = 0; i < 4; ++i) {
                    const int e = half + 2 * i;
                    const int es = (e < ce) ? e : 0;
                    const float ha = hh[es][32 + k], h1 = hh[es][k];
                    A1[i] = fmaf(ha, wf1, A1[i]); A2[i] = fmaf(ha, wf2, A2[i]);
                    A3[i] = fmaf(ha, wf3, A3[i]); A4[i] = fmaf(ha, wf4, A4[i]);
                    B1[i] = fmaf(h1, wl1, B1[i]); B2[i] = fmaf(h1, wl2, B2[i]);
                    B3[i] = fmaf(h1, wl3, B3[i]); B4[i] = fmaf(h1, wl4, B4[i]);
                }
            }
            const float inv32 = 1.0f / 32.0f;
#pragma unroll
            for (int i = 0; i < 4; ++i) {
                const int e = half + 2 * i;
                if (e < ce) {   // wave-uniform branch
                    const int src = srcs[e];
                    const float sh0 = shl[e][0], s1x = shl[e][1], s1y = shl[e][2], s1z = shl[e][3];
                    const float xs0 = selfx[(size_t)src * 512 + u];
                    const float* xvp = selfx + (size_t)src * 512 + 128 + 3 * u;
                    const float xvx = xvp[0], xvy = xvp[1], xvz = xvp[2];
                    const float w1 = A1[i] * B1[i] * inv32;
                    const float w2 = A2[i] * B2[i] * inv32;
                    const float w3 = A3[i] * B3[i] * inv32;
                    const float w4 = A4[i] * B4[i] * inv32;
                    const float dv = xvx * s1x + xvy * s1y + xvz * s1z;
                    acc0 += 0.5f * (w1 * xs0 * sh0 + w4 * dv * R3);
                    acc1 += C1V * (w2 * xs0 * s1x + w3 * xvx * sh0);
                    acc2 += C1V * (w2 * xs0 * s1y + w3 * xvy * sh0);
                    acc3 += C1V * (w2 * xs0 * s1z + w3 * xvz * sh0);
                }
            }
        }
        __syncthreads();
    }

    // cross-half reduce, add self_x, store
    if (half == 1) {
        float4 v = {acc0, acc1, acc2, acc3};
        *(float4*)(red + 4 * u) = v;
    }
    __syncthreads();
    if (half == 0) {
        float4 v = *(const float4*)(red + 4 * u);
        acc0 += v.x; acc1 += v.y; acc2 += v.z; acc3 += v.w;
        const size_t g = (size_t)dst * 512;
        accb[g + u] = acc0 + selfx[g + u];
        accb[g + 128 + 3 * u + 0] = acc1 + selfx[g + 128 + 3 * u + 0];
        accb[g + 128 + 3 * u + 1] = acc2 + selfx[g + 128 + 3 * u + 1];
        accb[g + 128 + 3 * u + 2] = acc3 + selfx[g + 128 + 3 * u + 2];
    }
}

extern "C" void kernel_launch(void* const* d_in, const int* in_sizes, int n_in,
                              void* d_out, int out_size, void* d_ws, size_t ws_size,
                              hipStream_t stream) {
    const float* x = (const float*)d_in[0];
    const int* edge_index = (const int*)d_in[1];
    const float* edge_attr = (const float*)d_in[2];
    const float* edge_sh = (const float*)d_in[3];
    const float* Wp0 = (const float*)d_in[4];
    const float* bp0 = (const float*)d_in[5];
    const float* Wp1 = (const float*)d_in[6];
    const float* ngW1 = (const float*)d_in[7];
    const float* ngb1 = (const float*)d_in[8];
    const float* ngW2 = (const float*)d_in[9];
    const float* ngb2 = (const float*)d_in[10];
    const float* Wn0 = (const float*)d_in[11];
    const float* bn0 = (const float*)d_in[12];
    const float* Wn1 = (const float*)d_in[13];
    const float* fcnW1 = (const float*)d_in[14];
    const float* fcnW2 = (const float*)d_in[15];
    const float* l0W1 = (const float*)d_in[16];
    const float* l0W2 = (const float*)d_in[17];
    const float* Wo0 = (const float*)d_in[18];
    const float* bo0 = (const float*)d_in[19];
    const float* Wo1 = (const float*)d_in[20];

    float* out = (float*)d_out;
    float* prex = out;                       // d_out as pre_x scratch (dead before final write)
    float* selfx = (float*)d_ws;
    float* accb = selfx + (size_t)NN * 512;
    int* deg = (int*)(accb + (size_t)NN * 512);
    int* cursor = deg + NN;
    int* row_ptr = cursor + NN;
    int* csr_eid = row_ptr + NN + 1;

    hipMemsetAsync(deg, 0, 2 * NN * sizeof(int), stream);  // deg + cursor

    k_irrep<<<NN / 16, 256, 0, stream>>>(x, Wp0, bp0, Wp1, prex);
    k_self<<<NN / 16, 256, 0, stream>>>(x, ngW1, ngb1, ngW2, ngb2, Wn0, bn0, Wn1, selfx);
    k_deg<<<EE / 256, 256, 0, stream>>>(edge_index, deg);
    k_scan<<<1, 1024, 0, stream>>>(deg, row_ptr);
    k_fill<<<EE / 256, 256, 0, stream>>>(edge_index, row_ptr, cursor, csr_eid);
    k_gather<<<NN, 256, 0, stream>>>(prex, selfx, edge_index, edge_attr, edge_sh,
                                     row_ptr, csr_eid, fcnW1, fcnW2, l0W1, l0W2, accb);
    k_irrep<<<NN / 16, 256, 0, stream>>>(accb, Wo0, bo0, Wo1, out);
}

// Round 3
// 963.553 us; speedup vs baseline: 4.7936x; 1.1006x over previous
//
#include <hip/hip_runtime.h>
#include <math.h>

#define NN 10000
#define EE 160000
#define CH 16

#define RS128 0.08838834764831845f   // 1/sqrt(128)
#define RS384 0.05103103630798287f   // 1/sqrt(384)
#define RS32  0.17677669529663687f   // 1/sqrt(32)
#define R3    0.57735026918962576f   // 1/sqrt(3)
#define C1V   0.86602540378443865f   // sqrt(3)/2

__device__ __forceinline__ float sspf(float x) {
    return fmaxf(x, 0.0f) + log1pf(__expf(-fabsf(x))) - 0.69314718055994530942f;
}

// out = irrep_linear(X, W0, b0, W1). In-place safe per block (stages tile first).
__global__ __launch_bounds__(256) void k_irrep(
    const float* __restrict__ X, const float* __restrict__ W0,
    const float* __restrict__ b0, const float* __restrict__ W1,
    float* __restrict__ out) {
    __shared__ float xs_t[16][128];
    __shared__ float xv_t[16][384];
    const int t = threadIdx.x;
    const int nb = blockIdx.x * 16;
    for (int idx = t; idx < 16 * 512; idx += 256) {
        int n = idx >> 9, c = idx & 511;
        float v = X[(size_t)(nb + n) * 512 + c];
        if (c < 128) xs_t[n][c] = v; else xv_t[n][c - 128] = v;
    }
    __syncthreads();
    const int col = t & 127, half = t >> 7;
    float accs[8] = {0, 0, 0, 0, 0, 0, 0, 0};
    float accv[24] = {0};
    for (int u = 0; u < 128; ++u) {
        float w0 = W0[u * 128 + col];
        float w1 = W1[u * 128 + col];
#pragma unroll
        for (int i = 0; i < 8; ++i) {
            int n = half * 8 + i;
            accs[i] = fmaf(xs_t[n][u], w0, accs[i]);
            accv[3 * i + 0] = fmaf(xv_t[n][3 * u + 0], w1, accv[3 * i + 0]);
            accv[3 * i + 1] = fmaf(xv_t[n][3 * u + 1], w1, accv[3 * i + 1]);
            accv[3 * i + 2] = fmaf(xv_t[n][3 * u + 2], w1, accv[3 * i + 2]);
        }
    }
    float bias = b0[col];
#pragma unroll
    for (int i = 0; i < 8; ++i) {
        size_t gn = (size_t)(nb + half * 8 + i) * 512;
        out[gn + col] = accs[i] * RS128 + bias;
        out[gn + 128 + 3 * col + 0] = accv[3 * i + 0] * RS128;
        out[gn + 128 + 3 * col + 1] = accv[3 * i + 1] * RS128;
        out[gn + 128 + 3 * col + 2] = accv[3 * i + 2] * RS128;
    }
}

// self_x = irrep_linear(norm_gate(x), Wn0, bn0, Wn1)
__global__ __launch_bounds__(256) void k_self(
    const float* __restrict__ X,
    const float* __restrict__ ngW1, const float* __restrict__ ngb1,
    const float* __restrict__ ngW2, const float* __restrict__ ngb2,
    const float* __restrict__ Wn0, const float* __restrict__ bn0,
    const float* __restrict__ Wn1,
    float* __restrict__ selfx) {
    __shared__ float xv_t[16][384];
    __shared__ float f0_t[16][256];
    __shared__ float t1_t[16][256];
    const int t = threadIdx.x;
    const int nb = blockIdx.x * 16;
    for (int idx = t; idx < 16 * 512; idx += 256) {
        int n = idx >> 9, c = idx & 511;
        float v = X[(size_t)(nb + n) * 512 + c];
        if (c < 128) f0_t[n][c] = v; else xv_t[n][c - 128] = v;
    }
    __syncthreads();
    for (int idx = t; idx < 16 * 128; idx += 256) {
        int n = idx >> 7, u = idx & 127;
        float a = xv_t[n][3 * u], b = xv_t[n][3 * u + 1], c = xv_t[n][3 * u + 2];
        f0_t[n][128 + u] = sqrtf(fmaf(a, a, fmaf(b, b, fmaf(c, c, 1e-12f))));
    }
    __syncthreads();
    {
        float acc[16] = {0};
        for (int k = 0; k < 256; ++k) {
            float w = ngW1[k * 256 + t];
#pragma unroll
            for (int n = 0; n < 16; ++n) acc[n] = fmaf(f0_t[n][k], w, acc[n]);
        }
        float b1 = ngb1[t];
#pragma unroll
        for (int n = 0; n < 16; ++n) {
            float z = acc[n] + b1;
            t1_t[n][t] = z * (1.0f / (1.0f + __expf(-z)));
        }
    }
    __syncthreads();
    {
        float acc[16] = {0};
        for (int k = 0; k < 256; ++k) {
            float w = ngW2[k * 256 + t];
#pragma unroll
            for (int n = 0; n < 16; ++n) acc[n] = fmaf(t1_t[n][k], w, acc[n]);
        }
        float b2 = ngb2[t];
#pragma unroll
        for (int n = 0; n < 16; ++n) f0_t[n][t] = acc[n] + b2;
    }
    __syncthreads();
    for (int idx = t; idx < 16 * 384; idx += 256) {
        int n = idx / 384, j = idx % 384;
        xv_t[n][j] *= f0_t[n][128 + j / 3];
    }
    __syncthreads();
    const int col = t & 127, half = t >> 7;
    float accs[8] = {0, 0, 0, 0, 0, 0, 0, 0};
    float accv[24] = {0};
    for (int u = 0; u < 128; ++u) {
        float w0 = Wn0[u * 128 + col];
        float w1 = Wn1[u * 128 + col];
#pragma unroll
        for (int i = 0; i < 8; ++i) {
            int n = half * 8 + i;
            accs[i] = fmaf(f0_t[n][u], w0, accs[i]);
            accv[3 * i + 0] = fmaf(xv_t[n][3 * u + 0], w1, accv[3 * i + 0]);
            accv[3 * i + 1] = fmaf(xv_t[n][3 * u + 1], w1, accv[3 * i + 1]);
            accv[3 * i + 2] = fmaf(xv_t[n][3 * u + 2], w1, accv[3 * i + 2]);
        }
    }
    float bias = bn0[col];
#pragma unroll
    for (int i = 0; i < 8; ++i) {
        size_t gn = (size_t)(nb + half * 8 + i) * 512;
        selfx[gn + col] = accs[i] * RS128 + bias;
        selfx[gn + 128 + 3 * col + 0] = accv[3 * i + 0] * RS128;
        selfx[gn + 128 + 3 * col + 1] = accv[3 * i + 1] * RS128;
        selfx[gn + 128 + 3 * col + 2] = accv[3 * i + 2] * RS128;
    }
}

// per-node halves of MLP1: pAB[n][0:32] = s_n @ l0W1[0:128], pAB[n][32:64] = s_n @ l0W1[128:256]
__global__ __launch_bounds__(256) void k_pre(
    const float* __restrict__ prex, const float* __restrict__ l0W1,
    float* __restrict__ pAB) {
    __shared__ float xs[8][128];
    const int t = threadIdx.x;
    const int nb = blockIdx.x * 8;
    for (int idx = t; idx < 8 * 128; idx += 256) {
        int n = idx >> 7, u = idx & 127;
        xs[n][u] = prex[(size_t)(nb + n) * 512 + u];
    }
    __syncthreads();
    const int n = t >> 5, k = t & 31;
    float a = 0, b = 0;
    for (int u = 0; u < 128; ++u) {
        float s = xs[n][u];
        a = fmaf(s, l0W1[u * 32 + k], a);
        b = fmaf(s, l0W1[(128 + u) * 32 + k], b);
    }
    pAB[(size_t)(nb + n) * 64 + k] = a;
    pAB[(size_t)(nb + n) * 64 + 32 + k] = b;
}

// ---- CSR build ----
__global__ __launch_bounds__(256) void k_deg(const int* __restrict__ ei, int* __restrict__ deg) {
    int e = blockIdx.x * 256 + threadIdx.x;
    if (e < EE) atomicAdd(&deg[ei[e]], 1);
}

__global__ __launch_bounds__(1024) void k_scan(const int* __restrict__ deg, int* __restrict__ row_ptr) {
    __shared__ int part[1024];
    const int t = threadIdx.x;
    const int base = t * 10;
    int loc[10];
    int s = 0;
#pragma unroll
    for (int i = 0; i < 10; ++i) {
        int idx = base + i;
        int d = (idx < NN) ? deg[idx] : 0;
        loc[i] = s;
        s += d;
    }
    part[t] = s;
    __syncthreads();
    for (int off = 1; off < 1024; off <<= 1) {
        int v = (t >= off) ? part[t - off] : 0;
        __syncthreads();
        part[t] += v;
        __syncthreads();
    }
    int excl = (t > 0) ? part[t - 1] : 0;
#pragma unroll
    for (int i = 0; i < 10; ++i) {
        int idx = base + i;
        if (idx <= NN) row_ptr[idx] = excl + loc[i];
    }
}

__global__ __launch_bounds__(256) void k_fill(const int* __restrict__ ei,
                                              const int* __restrict__ row_ptr,
                                              int* __restrict__ cursor,
                                              int* __restrict__ csr_eid) {
    int e = blockIdx.x * 256 + threadIdx.x;
    if (e < EE) {
        int d = ei[e];
        int pos = atomicAdd(&cursor[d], 1);
        csr_eid[row_ptr[d] + pos] = e;
    }
}

// ---- per-dst edge compute + aggregate (no atomics) ----
__global__ __launch_bounds__(256) void k_gather(
    const float* __restrict__ prex, const float* __restrict__ selfx,
    const float* __restrict__ pAB,
    const int* __restrict__ edge_index, const float* __restrict__ edge_attr,
    const float* __restrict__ edge_sh,
    const int* __restrict__ row_ptr, const int* __restrict__ csr_eid,
    const float* __restrict__ fcnW1, const float* __restrict__ fcnW2,
    const float* __restrict__ l0W1, const float* __restrict__ l0W2,
    float* __restrict__ accb) {
    const int dst = blockIdx.x;
    const int t = threadIdx.x;
    const int beg = row_ptr[dst];
    const int ne = row_ptr[dst + 1] - beg;

    __shared__ float dstv[384];
    __shared__ float pAd[32];
    __shared__ float ip[CH][128];
    __shared__ float ea[CH][32];
    __shared__ float hh[CH][64];
    __shared__ float shl[CH][4];
    __shared__ int srcs[CH];
    __shared__ int eidl[CH];
    __shared__ float red[512];

    for (int i = t; i < 384; i += 256) dstv[i] = prex[(size_t)dst * 512 + 128 + i];
    if (t < 32) pAd[t] = pAB[(size_t)dst * 64 + t];

    const int u = t & 127;
    const int half = t >> 7;
    float acc0 = 0, acc1 = 0, acc2 = 0, acc3 = 0;
    __syncthreads();

    for (int c0 = 0; c0 < ne; c0 += CH) {
        const int ce = min(CH, ne - c0);
        if (t < CH) {
            int id = csr_eid[beg + c0 + ((t < ce) ? t : 0)];
            eidl[t] = id;
            srcs[t] = edge_index[EE + id];
            const float4 s = *(const float4*)(edge_sh + (size_t)id * 4);
            shl[t][0] = s.x; shl[t][1] = s.y; shl[t][2] = s.z; shl[t][3] = s.w;
        }
        __syncthreads();

        // edge_attr tile + per-edge inner products
        for (int idx = t; idx < ce * 32; idx += 256) {
            int e = idx >> 5, j = idx & 31;
            ea[e][j] = edge_attr[(size_t)eidl[e] * 32 + j];
        }
        for (int idx = t; idx < ce * 128; idx += 256) {
            int e = idx >> 7, uu = idx & 127;
            const float* pv = prex + (size_t)srcs[e] * 512 + 128 + 3 * uu;
            ip[e][uu] = (dstv[3 * uu] * pv[0] + dstv[3 * uu + 1] * pv[1] +
                         dstv[3 * uu + 2] * pv[2]) * R3;
        }
        __syncthreads();

        // hidden units: h1 = ssp((pA[dst] + pB[src] + ip@Wc)/sqrt384), ha = ssp((ea@fcnW1)/sqrt32)
        {
            const int k = t & 31, ep = t >> 5;  // ep 0..7
#pragma unroll
            for (int h2 = 0; h2 < 2; ++h2) {
                const int e = ep + 8 * h2;
                if (e < ce) {
                    float a = pAd[k] + pAB[(size_t)srcs[e] * 64 + 32 + k];
#pragma unroll 4
                    for (int j = 0; j < 128; ++j)
                        a = fmaf(ip[e][j], l0W1[(256 + j) * 32 + k], a);
                    hh[e][k] = sspf(a * RS384);
                    float c = 0;
#pragma unroll
                    for (int j = 0; j < 32; ++j)
                        c = fmaf(ea[e][j], fcnW1[j * 32 + k], c);
                    hh[e][32 + k] = sspf(c * RS32);
                } else {
                    hh[e][k] = 0.0f;
                    hh[e][32 + k] = 0.0f;
                }
            }
        }
        __syncthreads();

        // phase C: thread owns column u; its half covers 8 of the 16 edge slots
        {
            float A[8][4], B[8][4];
#pragma unroll
            for (int i = 0; i < 8; ++i) {
#pragma unroll
                for (int q = 0; q < 4; ++q) { A[i][q] = 0; B[i][q] = 0; }
            }
            for (int k = 0; k < 32; ++k) {
                const float wf0 = fcnW2[k * 512 + u];
                const float wf1 = fcnW2[k * 512 + 128 + u];
                const float wf2 = fcnW2[k * 512 + 256 + u];
                const float wf3 = fcnW2[k * 512 + 384 + u];
                const float wl0 = l0W2[k * 512 + u];
                const float wl1 = l0W2[k * 512 + 128 + u];
                const float wl2 = l0W2[k * 512 + 256 + u];
                const float wl3 = l0W2[k * 512 + 384 + u];
#pragma unroll
                for (int i = 0; i < 8; ++i) {
                    const int e = half + 2 * i;
                    const float ha = hh[e][32 + k];
                    const float h1 = hh[e][k];
                    A[i][0] = fmaf(ha, wf0, A[i][0]);
                    A[i][1] = fmaf(ha, wf1, A[i][1]);
                    A[i][2] = fmaf(ha, wf2, A[i][2]);
                    A[i][3] = fmaf(ha, wf3, A[i][3]);
                    B[i][0] = fmaf(h1, wl0, B[i][0]);
                    B[i][1] = fmaf(h1, wl1, B[i][1]);
                    B[i][2] = fmaf(h1, wl2, B[i][2]);
                    B[i][3] = fmaf(h1, wl3, B[i][3]);
                }
            }
            const float inv32 = 1.0f / 32.0f;
#pragma unroll
            for (int i = 0; i < 8; ++i) {
                const int e = half + 2 * i;
                if (e >= ce) continue;  // wave-uniform (half is uniform per wave)
                const int src = srcs[e];
                const float sh0 = shl[e][0], s1x = shl[e][1], s1y = shl[e][2], s1z = shl[e][3];
                const float* sr = selfx + (size_t)src * 512;
                const float xs0 = sr[u];
                const float xvx = sr[128 + 3 * u], xvy = sr[128 + 3 * u + 1], xvz = sr[128 + 3 * u + 2];
                const float w1 = A[i][0] * B[i][0] * inv32;
                const float w2 = A[i][1] * B[i][1] * inv32;
                const float w3 = A[i][2] * B[i][2] * inv32;
                const float w4 = A[i][3] * B[i][3] * inv32;
                const float dv = xvx * s1x + xvy * s1y + xvz * s1z;
                acc0 += 0.5f * (w1 * xs0 * sh0 + w4 * dv * R3);
                acc1 += C1V * (w2 * xs0 * s1x + w3 * xvx * sh0);
                acc2 += C1V * (w2 * xs0 * s1y + w3 * xvy * sh0);
                acc3 += C1V * (w2 * xs0 * s1z + w3 * xvz * sh0);
            }
        }
        __syncthreads();
    }

    // cross-half reduce, add self_x, store
    if (half == 1) {
        float4 v = {acc0, acc1, acc2, acc3};
        *(float4*)(red + 4 * u) = v;
    }
    __syncthreads();
    if (half == 0) {
        float4 v = *(const float4*)(red + 4 * u);
        acc0 += v.x; acc1 += v.y; acc2 += v.z; acc3 += v.w;
        const size_t g = (size_t)dst * 512;
        accb[g + u] = acc0 + selfx[g + u];
        accb[g + 128 + 3 * u + 0] = acc1 + selfx[g + 128 + 3 * u + 0];
        accb[g + 128 + 3 * u + 1] = acc2 + selfx[g + 128 + 3 * u + 1];
        accb[g + 128 + 3 * u + 2] = acc3 + selfx[g + 128 + 3 * u + 2];
    }
}

extern "C" void kernel_launch(void* const* d_in, const int* in_sizes, int n_in,
                              void* d_out, int out_size, void* d_ws, size_t ws_size,
                              hipStream_t stream) {
    const float* x = (const float*)d_in[0];
    const int* edge_index = (const int*)d_in[1];
    const float* edge_attr = (const float*)d_in[2];
    const float* edge_sh = (const float*)d_in[3];
    const float* Wp0 = (const float*)d_in[4];
    const float* bp0 = (const float*)d_in[5];
    const float* Wp1 = (const float*)d_in[6];
    const float* ngW1 = (const float*)d_in[7];
    const float* ngb1 = (const float*)d_in[8];
    const float* ngW2 = (const float*)d_in[9];
    const float* ngb2 = (const float*)d_in[10];
    const float* Wn0 = (const float*)d_in[11];
    const float* bn0 = (const float*)d_in[12];
    const float* Wn1 = (const float*)d_in[13];
    const float* fcnW1 = (const float*)d_in[14];
    const float* fcnW2 = (const float*)d_in[15];
    const float* l0W1 = (const float*)d_in[16];
    const float* l0W2 = (const float*)d_in[17];
    const float* Wo0 = (const float*)d_in[18];
    const float* bo0 = (const float*)d_in[19];
    const float* Wo1 = (const float*)d_in[20];

    float* out = (float*)d_out;
    float* prex = out;                       // d_out as pre_x scratch (dead before final write)
    float* selfx = (float*)d_ws;
    float* accb = selfx + (size_t)NN * 512;
    int* deg = (int*)(accb + (size_t)NN * 512);
    int* cursor = deg + NN;
    int* row_ptr = cursor + NN;
    int* csr_eid = row_ptr + NN + 1;
    float* pAB = (float*)(csr_eid + EE);

    hipMemsetAsync(deg, 0, 2 * NN * sizeof(int), stream);  // deg + cursor

    k_irrep<<<NN / 16, 256, 0, stream>>>(x, Wp0, bp0, Wp1, prex);
    k_pre<<<NN / 8, 256, 0, stream>>>(prex, l0W1, pAB);
    k_self<<<NN / 16, 256, 0, stream>>>(x, ngW1, ngb1, ngW2, ngb2, Wn0, bn0, Wn1, selfx);
    k_deg<<<EE / 256, 256, 0, stream>>>(edge_index, deg);
    k_scan<<<1, 1024, 0, stream>>>(deg, row_ptr);
    k_fill<<<EE / 256, 256, 0, stream>>>(edge_index, row_ptr, cursor, csr_eid);
    k_gather<<<NN, 256, 0, stream>>>(prex, selfx, pAB, edge_index, edge_attr, edge_sh,
                                     row_ptr, csr_eid, fcnW1, fcnW2, l0W1, l0W2, accb);
    k_irrep<<<NN / 16, 256, 0, stream>>>(accb, Wo0, bo0, Wo1, out);
}

// Round 4
// 910.132 us; speedup vs baseline: 5.0750x; 1.0587x over previous
//
#include <hip/hip_runtime.h>
#include <math.h>

#define NN 10000
#define EE 160000
#define CH 8

#define RS128 0.08838834764831845f   // 1/sqrt(128)
#define RS384 0.05103103630798287f   // 1/sqrt(384)
#define RS32  0.17677669529663687f   // 1/sqrt(32)
#define R3    0.57735026918962576f   // 1/sqrt(3)
#define C1V   0.86602540378443865f   // sqrt(3)/2

__device__ __forceinline__ float sspf(float x) {
    return fmaxf(x, 0.0f) + log1pf(__expf(-fabsf(x))) - 0.69314718055994530942f;
}

// out = irrep_linear(X, W0, b0, W1). In-place safe per block (stages tile first).
__global__ __launch_bounds__(256) void k_irrep(
    const float* __restrict__ X, const float* __restrict__ W0,
    const float* __restrict__ b0, const float* __restrict__ W1,
    float* __restrict__ out) {
    __shared__ float xs_t[16][128];
    __shared__ float xv_t[16][384];
    const int t = threadIdx.x;
    const int nb = blockIdx.x * 16;
    for (int idx = t; idx < 16 * 512; idx += 256) {
        int n = idx >> 9, c = idx & 511;
        float v = X[(size_t)(nb + n) * 512 + c];
        if (c < 128) xs_t[n][c] = v; else xv_t[n][c - 128] = v;
    }
    __syncthreads();
    const int col = t & 127, half = t >> 7;
    float accs[8] = {0, 0, 0, 0, 0, 0, 0, 0};
    float accv[24] = {0};
    for (int u = 0; u < 128; ++u) {
        float w0 = W0[u * 128 + col];
        float w1 = W1[u * 128 + col];
#pragma unroll
        for (int i = 0; i < 8; ++i) {
            int n = half * 8 + i;
            accs[i] = fmaf(xs_t[n][u], w0, accs[i]);
            accv[3 * i + 0] = fmaf(xv_t[n][3 * u + 0], w1, accv[3 * i + 0]);
            accv[3 * i + 1] = fmaf(xv_t[n][3 * u + 1], w1, accv[3 * i + 1]);
            accv[3 * i + 2] = fmaf(xv_t[n][3 * u + 2], w1, accv[3 * i + 2]);
        }
    }
    float bias = b0[col];
#pragma unroll
    for (int i = 0; i < 8; ++i) {
        size_t gn = (size_t)(nb + half * 8 + i) * 512;
        out[gn + col] = accs[i] * RS128 + bias;
        out[gn + 128 + 3 * col + 0] = accv[3 * i + 0] * RS128;
        out[gn + 128 + 3 * col + 1] = accv[3 * i + 1] * RS128;
        out[gn + 128 + 3 * col + 2] = accv[3 * i + 2] * RS128;
    }
}

// self_x = irrep_linear(norm_gate(x), Wn0, bn0, Wn1)
__global__ __launch_bounds__(256) void k_self(
    const float* __restrict__ X,
    const float* __restrict__ ngW1, const float* __restrict__ ngb1,
    const float* __restrict__ ngW2, const float* __restrict__ ngb2,
    const float* __restrict__ Wn0, const float* __restrict__ bn0,
    const float* __restrict__ Wn1,
    float* __restrict__ selfx) {
    __shared__ float xv_t[16][384];
    __shared__ float f0_t[16][256];
    __shared__ float t1_t[16][256];
    const int t = threadIdx.x;
    const int nb = blockIdx.x * 16;
    for (int idx = t; idx < 16 * 512; idx += 256) {
        int n = idx >> 9, c = idx & 511;
        float v = X[(size_t)(nb + n) * 512 + c];
        if (c < 128) f0_t[n][c] = v; else xv_t[n][c - 128] = v;
    }
    __syncthreads();
    for (int idx = t; idx < 16 * 128; idx += 256) {
        int n = idx >> 7, u = idx & 127;
        float a = xv_t[n][3 * u], b = xv_t[n][3 * u + 1], c = xv_t[n][3 * u + 2];
        f0_t[n][128 + u] = sqrtf(fmaf(a, a, fmaf(b, b, fmaf(c, c, 1e-12f))));
    }
    __syncthreads();
    {
        float acc[16] = {0};
        for (int k = 0; k < 256; ++k) {
            float w = ngW1[k * 256 + t];
#pragma unroll
            for (int n = 0; n < 16; ++n) acc[n] = fmaf(f0_t[n][k], w, acc[n]);
        }
        float b1 = ngb1[t];
#pragma unroll
        for (int n = 0; n < 16; ++n) {
            float z = acc[n] + b1;
            t1_t[n][t] = z * (1.0f / (1.0f + __expf(-z)));
        }
    }
    __syncthreads();
    {
        float acc[16] = {0};
        for (int k = 0; k < 256; ++k) {
            float w = ngW2[k * 256 + t];
#pragma unroll
            for (int n = 0; n < 16; ++n) acc[n] = fmaf(t1_t[n][k], w, acc[n]);
        }
        float b2 = ngb2[t];
#pragma unroll
        for (int n = 0; n < 16; ++n) f0_t[n][t] = acc[n] + b2;
    }
    __syncthreads();
    for (int idx = t; idx < 16 * 384; idx += 256) {
        int n = idx / 384, j = idx % 384;
        xv_t[n][j] *= f0_t[n][128 + j / 3];
    }
    __syncthreads();
    const int col = t & 127, half = t >> 7;
    float accs[8] = {0, 0, 0, 0, 0, 0, 0, 0};
    float accv[24] = {0};
    for (int u = 0; u < 128; ++u) {
        float w0 = Wn0[u * 128 + col];
        float w1 = Wn1[u * 128 + col];
#pragma unroll
        for (int i = 0; i < 8; ++i) {
            int n = half * 8 + i;
            accs[i] = fmaf(f0_t[n][u], w0, accs[i]);
            accv[3 * i + 0] = fmaf(xv_t[n][3 * u + 0], w1, accv[3 * i + 0]);
            accv[3 * i + 1] = fmaf(xv_t[n][3 * u + 1], w1, accv[3 * i + 1]);
            accv[3 * i + 2] = fmaf(xv_t[n][3 * u + 2], w1, accv[3 * i + 2]);
        }
    }
    float bias = bn0[col];
#pragma unroll
    for (int i = 0; i < 8; ++i) {
        size_t gn = (size_t)(nb + half * 8 + i) * 512;
        selfx[gn + col] = accs[i] * RS128 + bias;
        selfx[gn + 128 + 3 * col + 0] = accv[3 * i + 0] * RS128;
        selfx[gn + 128 + 3 * col + 1] = accv[3 * i + 1] * RS128;
        selfx[gn + 128 + 3 * col + 2] = accv[3 * i + 2] * RS128;
    }
}

// per-node halves of MLP1: pAB[n][0:32] = s_n @ l0W1[0:128], pAB[n][32:64] = s_n @ l0W1[128:256]
__global__ __launch_bounds__(256) void k_pre(
    const float* __restrict__ prex, const float* __restrict__ l0W1,
    float* __restrict__ pAB) {
    __shared__ float xs[8][128];
    const int t = threadIdx.x;
    const int nb = blockIdx.x * 8;
    for (int idx = t; idx < 8 * 128; idx += 256) {
        int n = idx >> 7, u = idx & 127;
        xs[n][u] = prex[(size_t)(nb + n) * 512 + u];
    }
    __syncthreads();
    const int n = t >> 5, k = t & 31;
    float a = 0, b = 0;
    for (int u = 0; u < 128; ++u) {
        float s = xs[n][u];
        a = fmaf(s, l0W1[u * 32 + k], a);
        b = fmaf(s, l0W1[(128 + u) * 32 + k], b);
    }
    pAB[(size_t)(nb + n) * 64 + k] = a;
    pAB[(size_t)(nb + n) * 64 + 32 + k] = b;
}

// repack fcnW2,l0W2 -> Wpk[k][u][0:4]=fcnW2[k][u+128q], [4:8]=l0W2[k][u+128q]
__global__ __launch_bounds__(256) void k_wpack(
    const float* __restrict__ fcnW2, const float* __restrict__ l0W2,
    float* __restrict__ Wpk) {
    int idx = blockIdx.x * 256 + threadIdx.x;   // 32*128*8 = 32768
    int j = idx & 7, u = (idx >> 3) & 127, k = idx >> 10;
    float v = (j < 4) ? fcnW2[k * 512 + j * 128 + u] : l0W2[k * 512 + (j - 4) * 128 + u];
    Wpk[idx] = v;
}

// ---- CSR build ----
__global__ __launch_bounds__(256) void k_deg(const int* __restrict__ ei, int* __restrict__ deg) {
    int e = blockIdx.x * 256 + threadIdx.x;
    if (e < EE) atomicAdd(&deg[ei[e]], 1);
}

__global__ __launch_bounds__(1024) void k_scan(const int* __restrict__ deg, int* __restrict__ row_ptr) {
    __shared__ int part[1024];
    const int t = threadIdx.x;
    const int base = t * 10;
    int loc[10];
    int s = 0;
#pragma unroll
    for (int i = 0; i < 10; ++i) {
        int idx = base + i;
        int d = (idx < NN) ? deg[idx] : 0;
        loc[i] = s;
        s += d;
    }
    part[t] = s;
    __syncthreads();
    for (int off = 1; off < 1024; off <<= 1) {
        int v = (t >= off) ? part[t - off] : 0;
        __syncthreads();
        part[t] += v;
        __syncthreads();
    }
    int excl = (t > 0) ? part[t - 1] : 0;
#pragma unroll
    for (int i = 0; i < 10; ++i) {
        int idx = base + i;
        if (idx <= NN) row_ptr[idx] = excl + loc[i];
    }
}

__global__ __launch_bounds__(256) void k_fill(const int* __restrict__ ei,
                                              const int* __restrict__ row_ptr,
                                              int* __restrict__ cursor,
                                              int* __restrict__ csr_eid) {
    int e = blockIdx.x * 256 + threadIdx.x;
    if (e < EE) {
        int d = ei[e];
        int pos = atomicAdd(&cursor[d], 1);
        csr_eid[row_ptr[d] + pos] = e;
    }
}

// phase C: NP live edge slots per quarter (slots q, q+4)
template <int NP>
__device__ __forceinline__ void phaseC(
    int u, int q, int ce,
    const float2* __restrict__ hh2,                 // [8][32]
    const int* __restrict__ srcs, const float (*__restrict__ shl)[4],
    const float* __restrict__ Wpk, const float* __restrict__ selfx,
    float& acc0, float& acc1, float& acc2, float& acc3) {
    float A[NP][4], B[NP][4];
#pragma unroll
    for (int i = 0; i < NP; ++i) {
        A[i][0] = A[i][1] = A[i][2] = A[i][3] = 0;
        B[i][0] = B[i][1] = B[i][2] = B[i][3] = 0;
    }
#pragma unroll 4
    for (int k = 0; k < 32; ++k) {
        const float4 wf = *(const float4*)(Wpk + ((k << 7) + u) * 8);
        const float4 wl = *(const float4*)(Wpk + ((k << 7) + u) * 8 + 4);
#pragma unroll
        for (int i = 0; i < NP; ++i) {
            const float2 h = hh2[(q + 4 * i) * 32 + k];
            A[i][0] = fmaf(h.y, wf.x, A[i][0]);
            A[i][1] = fmaf(h.y, wf.y, A[i][1]);
            A[i][2] = fmaf(h.y, wf.z, A[i][2]);
            A[i][3] = fmaf(h.y, wf.w, A[i][3]);
            B[i][0] = fmaf(h.x, wl.x, B[i][0]);
            B[i][1] = fmaf(h.x, wl.y, B[i][1]);
            B[i][2] = fmaf(h.x, wl.z, B[i][2]);
            B[i][3] = fmaf(h.x, wl.w, B[i][3]);
        }
    }
    const float inv32 = 1.0f / 32.0f;
#pragma unroll
    for (int i = 0; i < NP; ++i) {
        const int e = q + 4 * i;
        if (e >= ce) continue;   // block-uniform per quarter-wave
        const int src = srcs[e];
        const float sh0 = shl[e][0], s1x = shl[e][1], s1y = shl[e][2], s1z = shl[e][3];
        const float* sr = selfx + (size_t)src * 512;
        const float xs0 = sr[u];
        const float xvx = sr[128 + 3 * u], xvy = sr[128 + 3 * u + 1], xvz = sr[128 + 3 * u + 2];
        const float w1 = A[i][0] * B[i][0] * inv32;
        const float w2 = A[i][1] * B[i][1] * inv32;
        const float w3 = A[i][2] * B[i][2] * inv32;
        const float w4 = A[i][3] * B[i][3] * inv32;
        const float dv = xvx * s1x + xvy * s1y + xvz * s1z;
        acc0 += 0.5f * (w1 * xs0 * sh0 + w4 * dv * R3);
        acc1 += C1V * (w2 * xs0 * s1x + w3 * xvx * sh0);
        acc2 += C1V * (w2 * xs0 * s1y + w3 * xvy * sh0);
        acc3 += C1V * (w2 * xs0 * s1z + w3 * xvz * sh0);
    }
}

// ---- per-dst edge compute + aggregate (no atomics) ----
__global__ __launch_bounds__(512) void k_gather(
    const float* __restrict__ prex, const float* __restrict__ selfx,
    const float* __restrict__ pAB,
    const int* __restrict__ edge_index, const float* __restrict__ edge_attr,
    const float* __restrict__ edge_sh,
    const int* __restrict__ row_ptr, const int* __restrict__ csr_eid,
    const float* __restrict__ fcnW1, const float* __restrict__ Wpk,
    const float* __restrict__ l0W1,
    float* __restrict__ accb) {
    const int dst = blockIdx.x;
    const int t = threadIdx.x;
    const int beg = row_ptr[dst];
    const int ne = row_ptr[dst + 1] - beg;

    __shared__ float dstv[384];
    __shared__ float pAd[32];
    __shared__ float ip[CH][128];
    __shared__ float ea[CH][32];
    __shared__ float2 hh2[CH * 32];
    __shared__ float shl[CH][4];
    __shared__ int srcs[CH];
    __shared__ int eidl[CH];
    __shared__ float red[3 * 512];

    for (int i = t; i < 384; i += 512) dstv[i] = prex[(size_t)dst * 512 + 128 + i];
    if (t < 32) pAd[t] = pAB[(size_t)dst * 64 + t];

    const int u = t & 127;
    const int q = t >> 7;    // quarter 0..3, wave-uniform
    float acc0 = 0, acc1 = 0, acc2 = 0, acc3 = 0;
    __syncthreads();

    for (int c0 = 0; c0 < ne; c0 += CH) {
        const int ce = min(CH, ne - c0);
        if (t < CH) {
            int id = csr_eid[beg + c0 + ((t < ce) ? t : 0)];
            eidl[t] = id;
            srcs[t] = edge_index[EE + id];
            const float4 s = *(const float4*)(edge_sh + (size_t)id * 4);
            shl[t][0] = s.x; shl[t][1] = s.y; shl[t][2] = s.z; shl[t][3] = s.w;
        }
        __syncthreads();

        // edge_attr tile + per-edge inner products
        for (int idx = t; idx < ce * 32; idx += 512) {
            int e = idx >> 5, j = idx & 31;
            ea[e][j] = edge_attr[(size_t)eidl[e] * 32 + j];
        }
        for (int idx = t; idx < ce * 128; idx += 512) {
            int e = idx >> 7, uu = idx & 127;
            const float* pv = prex + (size_t)srcs[e] * 512 + 128 + 3 * uu;
            ip[e][uu] = (dstv[3 * uu] * pv[0] + dstv[3 * uu + 1] * pv[1] +
                         dstv[3 * uu + 2] * pv[2]) * R3;
        }
        __syncthreads();

        // hidden: lower 256 threads -> h1 (.x), upper 256 -> ha (.y)
        {
            const int k = t & 31;
            if (t < 256) {
                const int e = t >> 5;
                float v = 0.0f;
                if (e < ce) {
                    float a = pAd[k] + pAB[(size_t)srcs[e] * 64 + 32 + k];
#pragma unroll 8
                    for (int j = 0; j < 128; j += 4) {
                        const float4 ipv = *(const float4*)&ip[e][j];
                        a = fmaf(ipv.x, l0W1[(256 + j) * 32 + k], a);
                        a = fmaf(ipv.y, l0W1[(257 + j) * 32 + k], a);
                        a = fmaf(ipv.z, l0W1[(258 + j) * 32 + k], a);
                        a = fmaf(ipv.w, l0W1[(259 + j) * 32 + k], a);
                    }
                    v = sspf(a * RS384);
                }
                ((float*)&hh2[e * 32 + k])[0] = v;
            } else {
                const int e = (t >> 5) - 8;
                float v = 0.0f;
                if (e < ce) {
                    float c = 0;
#pragma unroll
                    for (int j = 0; j < 32; ++j)
                        c = fmaf(ea[e][j], fcnW1[j * 32 + k], c);
                    v = sspf(c * RS32);
                }
                ((float*)&hh2[e * 32 + k])[1] = v;
            }
        }
        __syncthreads();

        if (ce > 4)
            phaseC<2>(u, q, ce, hh2, srcs, shl, Wpk, selfx, acc0, acc1, acc2, acc3);
        else
            phaseC<1>(u, q, ce, hh2, srcs, shl, Wpk, selfx, acc0, acc1, acc2, acc3);
        __syncthreads();
    }

    // cross-quarter reduce, add self_x, store
    if (q > 0) {
        float4 v = {acc0, acc1, acc2, acc3};
        *(float4*)(red + (q - 1) * 512 + 4 * u) = v;
    }
    __syncthreads();
    if (q == 0) {
#pragma unroll
        for (int j = 0; j < 3; ++j) {
            float4 v = *(const float4*)(red + j * 512 + 4 * u);
            acc0 += v.x; acc1 += v.y; acc2 += v.z; acc3 += v.w;
        }
        const size_t g = (size_t)dst * 512;
        accb[g + u] = acc0 + selfx[g + u];
        accb[g + 128 + 3 * u + 0] = acc1 + selfx[g + 128 + 3 * u + 0];
        accb[g + 128 + 3 * u + 1] = acc2 + selfx[g + 128 + 3 * u + 1];
        accb[g + 128 + 3 * u + 2] = acc3 + selfx[g + 128 + 3 * u + 2];
    }
}

extern "C" void kernel_launch(void* const* d_in, const int* in_sizes, int n_in,
                              void* d_out, int out_size, void* d_ws, size_t ws_size,
                              hipStream_t stream) {
    const float* x = (const float*)d_in[0];
    const int* edge_index = (const int*)d_in[1];
    const float* edge_attr = (const float*)d_in[2];
    const float* edge_sh = (const float*)d_in[3];
    const float* Wp0 = (const float*)d_in[4];
    const float* bp0 = (const float*)d_in[5];
    const float* Wp1 = (const float*)d_in[6];
    const float* ngW1 = (const float*)d_in[7];
    const float* ngb1 = (const float*)d_in[8];
    const float* ngW2 = (const float*)d_in[9];
    const float* ngb2 = (const float*)d_in[10];
    const float* Wn0 = (const float*)d_in[11];
    const float* bn0 = (const float*)d_in[12];
    const float* Wn1 = (const float*)d_in[13];
    const float* fcnW1 = (const float*)d_in[14];
    const float* fcnW2 = (const float*)d_in[15];
    const float* l0W1 = (const float*)d_in[16];
    const float* l0W2 = (const float*)d_in[17];
    const float* Wo0 = (const float*)d_in[18];
    const float* bo0 = (const float*)d_in[19];
    const float* Wo1 = (const float*)d_in[20];

    float* out = (float*)d_out;
    float* prex = out;                       // d_out as pre_x scratch (dead before final write)
    float* selfx = (float*)d_ws;
    float* accb = selfx + (size_t)NN * 512;
    int* deg = (int*)(accb + (size_t)NN * 512);
    int* cursor = deg + NN;
    int* row_ptr = cursor + NN;
    int* csr_eid = row_ptr + NN + 1;
    float* pAB = (float*)(csr_eid + EE);
    float* Wpk = pAB + (size_t)NN * 64;

    hipMemsetAsync(deg, 0, 2 * NN * sizeof(int), stream);  // deg + cursor

    k_irrep<<<NN / 16, 256, 0, stream>>>(x, Wp0, bp0, Wp1, prex);
    k_pre<<<NN / 8, 256, 0, stream>>>(prex, l0W1, pAB);
    k_wpack<<<128, 256, 0, stream>>>(fcnW2, l0W2, Wpk);
    k_self<<<NN / 16, 256, 0, stream>>>(x, ngW1, ngb1, ngW2, ngb2, Wn0, bn0, Wn1, selfx);
    k_deg<<<EE / 256, 256, 0, stream>>>(edge_index, deg);
    k_scan<<<1, 1024, 0, stream>>>(deg, row_ptr);
    k_fill<<<EE / 256, 256, 0, stream>>>(edge_index, row_ptr, cursor, csr_eid);
    k_gather<<<NN, 512, 0, stream>>>(prex, selfx, pAB, edge_index, edge_attr, edge_sh,
                                     row_ptr, csr_eid, fcnW1, Wpk, l0W1, accb);
    k_irrep<<<NN / 16, 256, 0, stream>>>(accb, Wo0, bo0, Wo1, out);
}